// Round 1
// baseline (39.534 us; speedup 1.0000x reference)
//
#include <hip/hip_runtime.h>
#include <hip/hip_bf16.h>

typedef __attribute__((ext_vector_type(4))) float f32x4;
typedef __attribute__((ext_vector_type(8))) short bf16x8;

#define N_NEI 64
#define D_IN  128
#define D_HID 128

__device__ __forceinline__ unsigned bfbits(float f) {
  unsigned u = __float_as_uint(f);
  return (u + 0x7fffu + ((u >> 16) & 1u)) >> 16;  // RNE fp32->bf16
}

union BF8 { bf16x8 v; unsigned u[4]; };

__device__ __forceinline__ bf16x8 pack8(const float4& a, const float4& b) {
  BF8 r;
  r.u[0] = bfbits(a.x) | (bfbits(a.y) << 16);
  r.u[1] = bfbits(a.z) | (bfbits(a.w) << 16);
  r.u[2] = bfbits(b.x) | (bfbits(b.y) << 16);
  r.u[3] = bfbits(b.z) | (bfbits(b.w) << 16);
  return r.v;
}

// Kernel 1: pooled[b][j] = max_n relu(neigh[b,n,:]·W_mlp[j,:] + b_mlp[j]), masked rows -> 0.
// One block = 4 batch rows. 4 waves, wave w owns M-tile rows w*16..w*16+15 (of 64 neighbors).
__global__ __launch_bounds__(256, 4)
void k1_pool(const float* __restrict__ neigh, const float* __restrict__ Wmlp,
             const float* __restrict__ bmlp, unsigned short* __restrict__ pooled) {
  __shared__ unsigned short Wl[D_HID * D_IN];  // 32KB bf16, row j = 256B, XOR-swizzled
  __shared__ float pool[4][D_HID];

  const int tid = threadIdx.x;
  const int l = tid & 63;
  const int w = tid >> 6;

  // stage W_mlp -> LDS bf16 (swizzled: byte = j*256 + ((d*2) ^ ((j&7)<<4)))
  const float4* W4 = (const float4*)Wmlp;
  #pragma unroll
  for (int it = 0; it < 8; ++it) {
    int f8 = it * 256 + tid;            // 8-float chunk id, 0..2047
    int j  = f8 >> 4;                   // row 0..127
    int d0 = (f8 & 15) * 8;             // col start
    float4 a = W4[f8 * 2];
    float4 b = W4[f8 * 2 + 1];
    int byte = j * 256 + ((d0 * 2) ^ ((j & 7) << 4));
    *(bf16x8*)((char*)Wl + byte) = pack8(a, b);
  }

  const int lr = l & 15;   // A row-in-tile / B col-in-tile
  const int lg = l >> 4;   // k-group

  float bml[8];
  #pragma unroll
  for (int t = 0; t < 8; ++t) bml[t] = bmlp[t * 16 + lr];

  __syncthreads();

  for (int i = 0; i < 4; ++i) {
    const int b = blockIdx.x * 4 + i;
    const float* arow = neigh + (size_t)(b * N_NEI + w * 16 + lr) * D_IN + lg * 8;

    // A fragments straight from global (fp32 -> bf16), plus fp32 row-sum for mask
    bf16x8 af[4];
    float rs = 0.f;
    #pragma unroll
    for (int ks = 0; ks < 4; ++ks) {
      float4 a0 = *(const float4*)(arow + ks * 32);
      float4 a1 = *(const float4*)(arow + ks * 32 + 4);
      rs += a0.x + a0.y + a0.z + a0.w + a1.x + a1.y + a1.z + a1.w;
      af[ks] = pack8(a0, a1);
    }
    rs += __shfl_xor(rs, 16);
    rs += __shfl_xor(rs, 32);   // rs = full fp32 row sum of neighbor (w*16+lr)
    unsigned mask16 = (unsigned)(__ballot(rs == 0.0f) & 0xFFFFull);  // bit r = row r masked

    f32x4 acc[8];
    #pragma unroll
    for (int t = 0; t < 8; ++t) acc[t] = (f32x4){0.f, 0.f, 0.f, 0.f};

    #pragma unroll
    for (int t = 0; t < 8; ++t) {
      #pragma unroll
      for (int ks = 0; ks < 4; ++ks) {
        int jr = t * 16 + lr;
        int d0 = ks * 32 + lg * 8;
        bf16x8 bf = *(const bf16x8*)((const char*)Wl + jr * 256 + ((d0 * 2) ^ ((jr & 7) << 4)));
        acc[t] = __builtin_amdgcn_mfma_f32_16x16x32_bf16(af[ks], bf, acc[t], 0, 0, 0);
      }
    }

    // relu + bias + mask, then max over the wave's 16 rows
    #pragma unroll
    for (int t = 0; t < 8; ++t) {
      float mt = 0.f;  // exact: masked entries are 0 and relu >= 0
      #pragma unroll
      for (int r = 0; r < 4; ++r) {
        int row = lg * 4 + r;          // D-layout: row = (l>>4)*4 + reg
        float v = fmaxf(acc[t][r] + bml[t], 0.f);
        if ((mask16 >> row) & 1u) v = 0.f;
        mt = fmaxf(mt, v);
      }
      mt = fmaxf(mt, __shfl_xor(mt, 16));
      mt = fmaxf(mt, __shfl_xor(mt, 32));
      if (l < 16) pool[w][t * 16 + l] = mt;
    }
    __syncthreads();
    if (tid < 128) {
      float p0 = fmaxf(pool[0][tid], pool[1][tid]);
      float p1 = fmaxf(pool[2][tid], pool[3][tid]);
      pooled[(size_t)b * D_HID + tid] = (unsigned short)bfbits(fmaxf(p0, p1));
    }
    __syncthreads();
  }
}

// Kernel 2: out[b][j] = relu([input|pooled][b,:]·W_comb[j,:] + b_comb[j])
// Block = 64 rows x 64 cols (quarter of output cols), K = 256.
__global__ __launch_bounds__(256, 4)
void k2_comb(const float* __restrict__ inp, const unsigned short* __restrict__ pooled,
             const float* __restrict__ Wcomb, const float* __restrict__ bcomb,
             float* __restrict__ out) {
  __shared__ unsigned short Wl[64 * 256];  // 32KB: 64 output cols x K=256, row = 512B, swizzled

  const int tid = threadIdx.x;
  const int l = tid & 63;
  const int w = tid >> 6;
  const int mchunk = blockIdx.x >> 2;   // 64-row chunk, 0..63
  const int colq   = blockIdx.x & 3;    // 64-col quarter

  const float4* W4 = (const float4*)Wcomb;
  #pragma unroll
  for (int it = 0; it < 8; ++it) {
    int c  = it * 256 + tid;            // 8-float chunk, 0..2047
    int jr = c >> 5;                    // 0..63
    int d0 = (c & 31) * 8;
    int gidx = ((colq * 64 + jr) * 256 + d0) >> 2;  // float4 index into W_comb
    float4 a = W4[gidx];
    float4 b = W4[gidx + 1];
    int byte = jr * 512 + ((d0 * 2) ^ ((jr & 7) << 4));
    *(bf16x8*)((char*)Wl + byte) = pack8(a, b);
  }

  const int lr = l & 15;
  const int lg = l >> 4;

  float bcl[4];
  #pragma unroll
  for (int t = 0; t < 4; ++t) bcl[t] = bcomb[colq * 64 + t * 16 + lr];

  __syncthreads();

  const int row = mchunk * 64 + w * 16 + lr;

  bf16x8 af[8];
  #pragma unroll
  for (int ks = 0; ks < 4; ++ks) {   // k < 128: fp32 input, convert
    const float* p = inp + (size_t)row * 128 + ks * 32 + lg * 8;
    float4 a0 = *(const float4*)p;
    float4 a1 = *(const float4*)(p + 4);
    af[ks] = pack8(a0, a1);
  }
  #pragma unroll
  for (int ks = 4; ks < 8; ++ks) {   // k >= 128: pooled already bf16
    af[ks] = *(const bf16x8*)(pooled + (size_t)row * 128 + (ks - 4) * 32 + lg * 8);
  }

  f32x4 acc[4];
  #pragma unroll
  for (int t = 0; t < 4; ++t) acc[t] = (f32x4){0.f, 0.f, 0.f, 0.f};
  #pragma unroll
  for (int t = 0; t < 4; ++t) {
    #pragma unroll
    for (int ks = 0; ks < 8; ++ks) {
      int jr = t * 16 + lr;
      int d0 = ks * 32 + lg * 8;
      bf16x8 bf = *(const bf16x8*)((const char*)Wl + jr * 512 + ((d0 * 2) ^ ((jr & 7) << 4)));
      acc[t] = __builtin_amdgcn_mfma_f32_16x16x32_bf16(af[ks], bf, acc[t], 0, 0, 0);
    }
  }

  #pragma unroll
  for (int t = 0; t < 4; ++t) {
    #pragma unroll
    for (int r = 0; r < 4; ++r) {
      int ro = mchunk * 64 + w * 16 + lg * 4 + r;
      int co = colq * 64 + t * 16 + lr;
      float v = acc[t][r] + bcl[t];
      out[(size_t)ro * 256 + co] = fmaxf(v, 0.f);
    }
  }
}

extern "C" void kernel_launch(void* const* d_in, const int* in_sizes, int n_in,
                              void* d_out, int out_size, void* d_ws, size_t ws_size,
                              hipStream_t stream) {
  const float* inp   = (const float*)d_in[0];
  const float* neigh = (const float*)d_in[1];
  const float* Wmlp  = (const float*)d_in[2];
  const float* bmlp  = (const float*)d_in[3];
  const float* Wcomb = (const float*)d_in[4];
  const float* bcomb = (const float*)d_in[5];
  float* out = (float*)d_out;
  unsigned short* pooled = (unsigned short*)d_ws;  // [4096][128] bf16, 1 MB

  k1_pool<<<1024, 256, 0, stream>>>(neigh, Wmlp, bmlp, pooled);
  k2_comb<<<256, 256, 0, stream>>>(inp, pooled, Wcomb, bcomb, out);
}